// Round 5
// baseline (101.701 us; speedup 1.0000x reference)
//
#include <hip/hip_runtime.h>
#include <hip/hip_bf16.h>

// ARAP local step, round 5.
// Rounds 2-4 established: timed window carries a ~85-90us harness floor
// (268MB d_ws re-poison fills at 43us each + input restores dominate the
// profile; our kernels never enter the top-5). Strategy: minimize our share.
// Two kernels, no workspace round-trip:
//   1) prepack: xyz1/xyz2 -> 32B/vertex record (2 dwordx4 per gather later,
//      3x less TA address processing than 6 scalar dwords).
//   2) fused gather+solve: 4 lanes/vertex (6250 waves, 8 waves/SIMD), int4/
//      float4 coalesced idx+weight loads, 4 unrolled dwordx4-pair gathers per
//      lane (deep MLP), 2-step shfl_xor covariance reduction, then ALL lanes
//      redundantly run the eigensolve (branch-free, no LDS/barrier; redundant
//      VALU overlaps other waves' VMEM), lane 0 writes R.
// Eigensolve: Horn quaternion via 16 symmetric squarings of shifted PD 4x4
// (gap-independent convergence; verified rounds 2-4, absmax 3.9e-3).

__global__ __launch_bounds__(256)
void prepack_kernel(const float* __restrict__ xyz1,
                    const float* __restrict__ xyz2,
                    float4* __restrict__ pk,   // [B*N][2] float4 (32B/vertex)
                    int total)
{
    int t = blockIdx.x * blockDim.x + threadIdx.x;
    if (t >= total) return;
    float4 a, c;
    a.x = xyz1[t * 3 + 0]; a.y = xyz1[t * 3 + 1]; a.z = xyz1[t * 3 + 2]; a.w = 0.f;
    c.x = xyz2[t * 3 + 0]; c.y = xyz2[t * 3 + 1]; c.z = xyz2[t * 3 + 2]; c.w = 0.f;
    pk[2 * (size_t)t + 0] = a;
    pk[2 * (size_t)t + 1] = c;
}

// 4 lanes per (b,i) vertex: lane u handles neighbors u, u+4, u+8, u+12.
__global__ __launch_bounds__(256)
void arap_fused_kernel(const float4* __restrict__ pk,
                       const int*   __restrict__ nbr,
                       const int*   __restrict__ num,
                       const int*   __restrict__ acc,
                       const float* __restrict__ wgt,
                       float*       __restrict__ out,
                       int B, int N)
{
    int tid = blockIdx.x * blockDim.x + threadIdx.x;
    int v = tid >> 2;          // vertex work-item (b*N + i)
    int u = tid & 3;           // sub-lane within the 4-lane vertex group
    int total = B * N;
    if (v >= total) return;    // whole 4-lane group exits together
    int b = v / N;
    int i = v - b * N;

    const float4* base = pk + 2 * (size_t)b * N;
    float4 P1 = base[2 * i + 0];   // 4 lanes same address
    float4 P2 = base[2 * i + 1];

    int a0  = acc[i];
    int cnt = num[i];

    float Sxx = 0.f, Sxy = 0.f, Sxz = 0.f;
    float Syx = 0.f, Syy = 0.f, Syz = 0.f;
    float Szx = 0.f, Szy = 0.f, Szz = 0.f;

    if (cnt == 16 && (a0 & 3) == 0) {
        // Coalesced: per lane one int4 + one float4 (wave covers 1KB runs).
        int4   jj = ((const int4*)(nbr + a0))[u];
        float4 ww = ((const float4*)(wgt + a0))[u];
        int   js[4] = {jj.x, jj.y, jj.z, jj.w};
        float ws[4] = {ww.x, ww.y, ww.z, ww.w};
#pragma unroll
        for (int r = 0; r < 4; ++r) {
            int j = js[r];
            float4 A = base[2 * j + 0];   // A,C share one 64B line (32B rec)
            float4 C = base[2 * j + 1];
            float we = ws[r];
            float d1x = P1.x - A.x, d1y = P1.y - A.y, d1z = P1.z - A.z;
            float d2x = P2.x - C.x, d2y = P2.y - C.y, d2z = P2.z - C.z;
            float w1x = we * d1x, w1y = we * d1y, w1z = we * d1z;
            Sxx += w1x * d2x;  Sxy += w1x * d2y;  Sxz += w1x * d2z;
            Syx += w1y * d2x;  Syy += w1y * d2y;  Syz += w1y * d2z;
            Szx += w1z * d2x;  Szy += w1z * d2y;  Szz += w1z * d2z;
        }
    } else {
        for (int kk = u; kk < cnt; kk += 4) {
            int   e  = a0 + kk;
            int   j  = nbr[e];
            float we = wgt[e];
            float4 A = base[2 * j + 0];
            float4 C = base[2 * j + 1];
            float d1x = P1.x - A.x, d1y = P1.y - A.y, d1z = P1.z - A.z;
            float d2x = P2.x - C.x, d2y = P2.y - C.y, d2z = P2.z - C.z;
            float w1x = we * d1x, w1y = we * d1y, w1z = we * d1z;
            Sxx += w1x * d2x;  Sxy += w1x * d2y;  Sxz += w1x * d2z;
            Syx += w1y * d2x;  Syy += w1y * d2y;  Syz += w1y * d2z;
            Szx += w1z * d2x;  Szy += w1z * d2y;  Szz += w1z * d2z;
        }
    }

    // Reduce across the 4-lane group (xor 1,2 stay in-group).
#pragma unroll
    for (int m = 2; m >= 1; m >>= 1) {
        Sxx += __shfl_xor(Sxx, m);  Sxy += __shfl_xor(Sxy, m);  Sxz += __shfl_xor(Sxz, m);
        Syx += __shfl_xor(Syx, m);  Syy += __shfl_xor(Syy, m);  Syz += __shfl_xor(Syz, m);
        Szx += __shfl_xor(Szx, m);  Szy += __shfl_xor(Szy, m);  Szz += __shfl_xor(Szz, m);
    }

    // All 4 lanes now hold S; all compute the solve redundantly (branch-free),
    // lane u==0 writes. Horn's 4x4 (q=[w,x,y,z]); maps d1 -> d2.
    float n00 =  Sxx + Syy + Szz;
    float n01 =  Syz - Szy;
    float n02 =  Szx - Sxz;
    float n03 =  Sxy - Syx;
    float n11 =  Sxx - Syy - Szz;
    float n12 =  Sxy + Syx;
    float n13 =  Szx + Sxz;
    float n22 = -Sxx + Syy - Szz;
    float n23 =  Syz + Szy;
    float n33 = -Sxx - Syy + Szz;

    float fro2 = Sxx*Sxx + Sxy*Sxy + Sxz*Sxz
               + Syx*Syx + Syy*Syy + Syz*Syz
               + Szx*Szx + Szy*Szy + Szz*Szz;
    float s = 2.0f * sqrtf(fro2) + 1e-30f;

    float m00 = n00 + s, m01 = n01, m02 = n02, m03 = n03;
    float m11 = n11 + s, m12 = n12, m13 = n13;
    float m22 = n22 + s, m23 = n23;
    float m33 = n33 + s;

    {
        float inv = 1.0f / (m00 + m11 + m22 + m33);
        m00 *= inv; m01 *= inv; m02 *= inv; m03 *= inv;
        m11 *= inv; m12 *= inv; m13 *= inv;
        m22 *= inv; m23 *= inv; m33 *= inv;
    }

    // 16 symmetric squarings with trace renorm: M^(2^16) -> c*v*v^T.
#pragma unroll
    for (int it = 0; it < 16; ++it) {
        float p00 = m00*m00 + m01*m01 + m02*m02 + m03*m03;
        float p01 = m00*m01 + m01*m11 + m02*m12 + m03*m13;
        float p02 = m00*m02 + m01*m12 + m02*m22 + m03*m23;
        float p03 = m00*m03 + m01*m13 + m02*m23 + m03*m33;
        float p11 = m01*m01 + m11*m11 + m12*m12 + m13*m13;
        float p12 = m01*m02 + m11*m12 + m12*m22 + m13*m23;
        float p13 = m01*m03 + m11*m13 + m12*m23 + m13*m33;
        float p22 = m02*m02 + m12*m12 + m22*m22 + m23*m23;
        float p23 = m02*m03 + m12*m13 + m22*m23 + m23*m33;
        float p33 = m03*m03 + m13*m13 + m23*m23 + m33*m33;
        float inv = 1.0f / (p00 + p11 + p22 + p33);
        m00 = p00 * inv; m01 = p01 * inv; m02 = p02 * inv; m03 = p03 * inv;
        m11 = p11 * inv; m12 = p12 * inv; m13 = p13 * inv;
        m22 = p22 * inv; m23 = p23 * inv;
        m33 = p33 * inv;
    }

    // Column with the largest diagonal entry == top eigenvector.
    float qw = m00, qx = m01, qy = m02, qz = m03, best = m00;
    {
        bool g = m11 > best;
        qw = g ? m01 : qw; qx = g ? m11 : qx; qy = g ? m12 : qy; qz = g ? m13 : qz;
        best = g ? m11 : best;
        g = m22 > best;
        qw = g ? m02 : qw; qx = g ? m12 : qx; qy = g ? m22 : qy; qz = g ? m23 : qz;
        best = g ? m22 : best;
        g = m33 > best;
        qw = g ? m03 : qw; qx = g ? m13 : qx; qy = g ? m23 : qy; qz = g ? m33 : qz;
    }
    {
        float inv = rsqrtf(qw*qw + qx*qx + qy*qy + qz*qz);
        qw *= inv; qx *= inv; qy *= inv; qz *= inv;
    }

    if (u == 0) {
        float xx = qx*qx, yy = qy*qy, zz = qz*qz;
        float xy = qx*qy, xz = qx*qz, yz = qy*qz;
        float wx = qw*qx, wy = qw*qy, wz = qw*qz;
        float* o = out + (size_t)v * 9;
        o[0] = 1.f - 2.f*(yy + zz);
        o[1] = 2.f*(xy - wz);
        o[2] = 2.f*(xz + wy);
        o[3] = 2.f*(xy + wz);
        o[4] = 1.f - 2.f*(xx + zz);
        o[5] = 2.f*(yz - wx);
        o[6] = 2.f*(xz - wy);
        o[7] = 2.f*(yz + wx);
        o[8] = 1.f - 2.f*(xx + yy);
    }
}

extern "C" void kernel_launch(void* const* d_in, const int* in_sizes, int n_in,
                              void* d_out, int out_size, void* d_ws, size_t ws_size,
                              hipStream_t stream) {
    const float* xyz1 = (const float*)d_in[0];
    const float* xyz2 = (const float*)d_in[1];
    const int*   nbr  = (const int*)  d_in[2];
    const int*   num  = (const int*)  d_in[3];
    const int*   acc  = (const int*)  d_in[4];
    const float* wgt  = (const float*)d_in[5];
    float* out = (float*)d_out;

    int N = in_sizes[3];               // numNeighbors has N entries
    int B = in_sizes[0] / (N * 3);     // xyz1 is [B,N,3]
    int total = B * N;

    float4* pk = (float4*)d_ws;        // [total][2] float4 = 32B/vertex

    int block = 256;
    prepack_kernel<<<(total + block - 1) / block, block, 0, stream>>>(
        xyz1, xyz2, pk, total);
    int fthreads = total * 4;
    arap_fused_kernel<<<(fthreads + block - 1) / block, block, 0, stream>>>(
        pk, nbr, num, acc, wgt, out, B, N);
}

// Round 6
// 95.397 us; speedup vs baseline: 1.0661x; 1.0661x over previous
//
#include <hip/hip_runtime.h>
#include <hip/hip_bf16.h>

// ARAP local step — final structure (round-3 kernel, measured best: 94.0us).
//
// Ledger: R2=99.3 (1 kernel, 96 scalar divergent gathers/thread),
// R3=94.0 (this), R4=100.6 (3 kernels, 16-lane edge-parallel), R5=101.7
// (4-lane + 4x-redundant solve). R4/R5 regressions are explained: extra
// launches/round-trips and redundant eigensolve VALU; the timed window also
// carries a ~85-90us harness floor (268MB d_ws 0xAA re-poison fill at ~78%
// HBM peak + input-restore dispatch train dominate every rocprof top-5; our
// kernels never appear). Controllable share is ~5-8us.
//
// Structure:
//  1) prepack: xyz1/xyz2 -> one 32B/vertex record {x1,y1,z1,_,x2,y2,z2,_} so
//     each neighbor gather is 2x global_load_dwordx4 hitting one 64B line
//     (3x less TA address processing than 6 scalar dword gathers).
//  2) fused: 1 thread/vertex, int4/float4 coalesced index+weight loads,
//     fully unrolled 16-neighbor gather (deep MLP), then Horn-quaternion
//     eigensolve: 16 symmetric squarings of the shifted PD 4x4
//     M = N + 2||S||_F I  =>  M^(2^16) ~= c v v^T; column with largest
//     diagonal == top eigenvector == optimal quaternion. Gap-independent
//     convergence (fixes round-1 power-iteration tail); includes the SVD
//     reflection fix by construction. Verified absmax 3.9e-3 (thr 2e-2).

__global__ __launch_bounds__(256)
void prepack_kernel(const float* __restrict__ xyz1,
                    const float* __restrict__ xyz2,
                    float4* __restrict__ pk,   // [B*N][2] float4
                    int total)
{
    int t = blockIdx.x * blockDim.x + threadIdx.x;
    if (t >= total) return;
    float4 a, c;
    a.x = xyz1[t * 3 + 0]; a.y = xyz1[t * 3 + 1]; a.z = xyz1[t * 3 + 2]; a.w = 0.f;
    c.x = xyz2[t * 3 + 0]; c.y = xyz2[t * 3 + 1]; c.z = xyz2[t * 3 + 2]; c.w = 0.f;
    pk[2 * (size_t)t + 0] = a;
    pk[2 * (size_t)t + 1] = c;
}

__global__ __launch_bounds__(256)
void arap_rot_kernel(const float4* __restrict__ pk,
                     const int*   __restrict__ nbr,
                     const int*   __restrict__ num,
                     const int*   __restrict__ acc,
                     const float* __restrict__ wgt,
                     float*       __restrict__ out,
                     int B, int N)
{
    int t = blockIdx.x * blockDim.x + threadIdx.x;
    int total = B * N;
    if (t >= total) return;
    int b = t / N;
    int i = t - b * N;

    const float4* base = pk + 2 * (size_t)b * N;

    float4 P1 = base[2 * i + 0];
    float4 P2 = base[2 * i + 1];
    float p1x = P1.x, p1y = P1.y, p1z = P1.z;
    float p2x = P2.x, p2y = P2.y, p2z = P2.z;

    float Sxx = 0.f, Sxy = 0.f, Sxz = 0.f;
    float Syx = 0.f, Syy = 0.f, Syz = 0.f;
    float Szx = 0.f, Szy = 0.f, Szz = 0.f;

    int a0  = acc[i];
    int cnt = num[i];

    if (cnt == 16 && (a0 & 3) == 0) {
        // Fast path: 4 int4 index loads, 4 float4 weight loads, 32 dwordx4
        // gathers (pairs share a 64B line). Fully unrolled for MLP.
        const int4*   nb4 = (const int4*)(nbr + a0);
        const float4* w4  = (const float4*)(wgt + a0);
#pragma unroll
        for (int c = 0; c < 4; ++c) {
            int4   jj = nb4[c];
            float4 ww = w4[c];
            int js[4] = {jj.x, jj.y, jj.z, jj.w};
            float ws[4] = {ww.x, ww.y, ww.z, ww.w};
#pragma unroll
            for (int u = 0; u < 4; ++u) {
                int j = js[u];
                float4 A = base[2 * j + 0];
                float4 C = base[2 * j + 1];
                float we = ws[u];
                float d1x = p1x - A.x, d1y = p1y - A.y, d1z = p1z - A.z;
                float d2x = p2x - C.x, d2y = p2y - C.y, d2z = p2z - C.z;
                float w1x = we * d1x, w1y = we * d1y, w1z = we * d1z;
                Sxx += w1x * d2x;  Sxy += w1x * d2y;  Sxz += w1x * d2z;
                Syx += w1y * d2x;  Syy += w1y * d2y;  Syz += w1y * d2z;
                Szx += w1z * d2x;  Szy += w1z * d2y;  Szz += w1z * d2z;
            }
        }
    } else {
        for (int k = 0; k < cnt; ++k) {
            int   e  = a0 + k;
            int   j  = nbr[e];
            float we = wgt[e];
            float4 A = base[2 * j + 0];
            float4 C = base[2 * j + 1];
            float d1x = p1x - A.x, d1y = p1y - A.y, d1z = p1z - A.z;
            float d2x = p2x - C.x, d2y = p2y - C.y, d2z = p2z - C.z;
            float w1x = we * d1x, w1y = we * d1y, w1z = we * d1z;
            Sxx += w1x * d2x;  Sxy += w1x * d2y;  Sxz += w1x * d2z;
            Syx += w1y * d2x;  Syy += w1y * d2y;  Syz += w1y * d2z;
            Szx += w1z * d2x;  Szy += w1z * d2y;  Szz += w1z * d2z;
        }
    }

    // Horn's 4x4 symmetric matrix (q = [w,x,y,z] basis); maps d1 -> d2.
    float n00 =  Sxx + Syy + Szz;
    float n01 =  Syz - Szy;
    float n02 =  Szx - Sxz;
    float n03 =  Sxy - Syx;
    float n11 =  Sxx - Syy - Szz;
    float n12 =  Sxy + Syx;
    float n13 =  Szx + Sxz;
    float n22 = -Sxx + Syy - Szz;
    float n23 =  Syz + Szy;
    float n33 = -Sxx - Syy + Szz;

    // Shift: all |eig(N)| <= sqrt(3)*||S||_F < 2*||S||_F  => M = N+sI is PD,
    // top eigvec of M == Horn's quaternion.
    float fro2 = Sxx*Sxx + Sxy*Sxy + Sxz*Sxz
               + Syx*Syx + Syy*Syy + Syz*Syz
               + Szx*Szx + Szy*Szy + Szz*Szz;
    float s = 2.0f * sqrtf(fro2) + 1e-30f;

    float m00 = n00 + s, m01 = n01, m02 = n02, m03 = n03;
    float m11 = n11 + s, m12 = n12, m13 = n13;
    float m22 = n22 + s, m23 = n23;
    float m33 = n33 + s;

    {
        float inv = 1.0f / (m00 + m11 + m22 + m33);
        m00 *= inv; m01 *= inv; m02 *= inv; m03 *= inv;
        m11 *= inv; m12 *= inv; m13 *= inv;
        m22 *= inv; m23 *= inv; m33 *= inv;
    }

    // 16 symmetric squarings with trace renormalization: M^(2^16) -> c*v*v^T.
#pragma unroll
    for (int it = 0; it < 16; ++it) {
        float p00 = m00*m00 + m01*m01 + m02*m02 + m03*m03;
        float p01 = m00*m01 + m01*m11 + m02*m12 + m03*m13;
        float p02 = m00*m02 + m01*m12 + m02*m22 + m03*m23;
        float p03 = m00*m03 + m01*m13 + m02*m23 + m03*m33;
        float p11 = m01*m01 + m11*m11 + m12*m12 + m13*m13;
        float p12 = m01*m02 + m11*m12 + m12*m22 + m13*m23;
        float p13 = m01*m03 + m11*m13 + m12*m23 + m13*m33;
        float p22 = m02*m02 + m12*m12 + m22*m22 + m23*m23;
        float p23 = m02*m03 + m12*m13 + m22*m23 + m23*m33;
        float p33 = m03*m03 + m13*m13 + m23*m23 + m33*m33;
        float inv = 1.0f / (p00 + p11 + p22 + p33);
        m00 = p00 * inv; m01 = p01 * inv; m02 = p02 * inv; m03 = p03 * inv;
        m11 = p11 * inv; m12 = p12 * inv; m13 = p13 * inv;
        m22 = p22 * inv; m23 = p23 * inv;
        m33 = p33 * inv;
    }

    // Column with the largest diagonal entry == top eigenvector.
    float qw = m00, qx = m01, qy = m02, qz = m03, best = m00;
    {
        bool g = m11 > best;
        qw = g ? m01 : qw; qx = g ? m11 : qx; qy = g ? m12 : qy; qz = g ? m13 : qz;
        best = g ? m11 : best;
        g = m22 > best;
        qw = g ? m02 : qw; qx = g ? m12 : qx; qy = g ? m22 : qy; qz = g ? m23 : qz;
        best = g ? m22 : best;
        g = m33 > best;
        qw = g ? m03 : qw; qx = g ? m13 : qx; qy = g ? m23 : qy; qz = g ? m33 : qz;
    }
    {
        float inv = rsqrtf(qw*qw + qx*qx + qy*qy + qz*qz);
        qw *= inv; qx *= inv; qy *= inv; qz *= inv;
    }

    // Quaternion -> rotation matrix (R d1 ~= d2), row-major 3x3
    float xx = qx*qx, yy = qy*qy, zz = qz*qz;
    float xy = qx*qy, xz = qx*qz, yz = qy*qz;
    float wx = qw*qx, wy = qw*qy, wz = qw*qz;

    float* o = out + (size_t)t * 9;
    o[0] = 1.f - 2.f*(yy + zz);
    o[1] = 2.f*(xy - wz);
    o[2] = 2.f*(xz + wy);
    o[3] = 2.f*(xy + wz);
    o[4] = 1.f - 2.f*(xx + zz);
    o[5] = 2.f*(yz - wx);
    o[6] = 2.f*(xz - wy);
    o[7] = 2.f*(yz + wx);
    o[8] = 1.f - 2.f*(xx + yy);
}

extern "C" void kernel_launch(void* const* d_in, const int* in_sizes, int n_in,
                              void* d_out, int out_size, void* d_ws, size_t ws_size,
                              hipStream_t stream) {
    const float* xyz1 = (const float*)d_in[0];
    const float* xyz2 = (const float*)d_in[1];
    const int*   nbr  = (const int*)  d_in[2];
    const int*   num  = (const int*)  d_in[3];
    const int*   acc  = (const int*)  d_in[4];
    const float* wgt  = (const float*)d_in[5];
    float* out = (float*)d_out;

    int N = in_sizes[3];               // numNeighbors has N entries
    int B = in_sizes[0] / (N * 3);     // xyz1 is [B,N,3]
    int total = B * N;

    float4* pk = (float4*)d_ws;        // [total][2] float4 = 32B/vertex

    int block = 256;
    int grid = (total + block - 1) / block;
    prepack_kernel<<<grid, block, 0, stream>>>(xyz1, xyz2, pk, total);
    arap_rot_kernel<<<grid, block, 0, stream>>>(pk, nbr, num, acc, wgt,
                                                out, B, N);
}